// Round 7
// baseline (4147.143 us; speedup 1.0000x reference)
//
#include <hip/hip_runtime.h>
#include <math.h>

#define NB 8192     // batch rows
#define DD 512      // hidden dim
#define KC 4096     // codebook size
#define NL 4        // layers

#define NTB 32      // part[] column tiles (128 codes each)
#define MARGIN 4.0f // bf16-dot candidate margin (>> 2*max bf16 dot error ~0.3)

#define GBM 256
#define GBN 256

typedef __bf16 bf16x8 __attribute__((ext_vector_type(8)));
typedef float  f32x4  __attribute__((ext_vector_type(4)));
typedef unsigned short u16;

struct Top2 { float v1; int i1; float v2; int i2; };

__device__ __forceinline__ u16 f2bf(float f) {   // RNE fp32 -> bf16
    unsigned u = __float_as_uint(f);
    return (u16)((u + 0x7fffu + ((u >> 16) & 1u)) >> 16);
}

__device__ __forceinline__ void top2_insert(float v, int idx, float& v1, int& i1, float& v2, int& i2) {
    if (v > v1 || (v == v1 && idx < i1)) { v2 = v1; i2 = i1; v1 = v; i1 = idx; }
    else if (v > v2 || (v == v2 && idx < i2)) { v2 = v; i2 = idx; }
}

__device__ __forceinline__ void pick_better(float av, int ai, float bv, int bi, float& ov, int& oi) {
    if (av > bv || (av == bv && ai < bi)) { ov = av; oi = ai; } else { ov = bv; oi = bi; }
}

// fp32 -> bf16 bulk convert (n4 = count/4)
__global__ __launch_bounds__(256)
void k_cvt_bf16(const float* __restrict__ src, u16* __restrict__ dst, int n4)
{
    const int i = blockIdx.x * 256 + threadIdx.x;
    if (i < n4) {
        const float4 f = ((const float4*)src)[i];
        uint2 p;
        p.x = (unsigned)f2bf(f.x) | ((unsigned)f2bf(f.y) << 16);
        p.y = (unsigned)f2bf(f.z) | ((unsigned)f2bf(f.w) << 16);
        ((uint2*)dst)[i] = p;
    }
}

// ===================== REAL GEMM (R5 structure, unchanged) =====================
__global__ __launch_bounds__(512, 2)
void k_simtop2(const u16* __restrict__ Rb, const u16* __restrict__ Cb,
               Top2* __restrict__ part /* [NB][NTB] */)
{
    __shared__ __align__(16) u16 As[2][8192];
    __shared__ __align__(16) u16 Bs[2][8192];

    const int tid  = threadIdx.x;
    const int lane = tid & 63;
    const int w    = tid >> 6;
    const int wm   = w >> 2;
    const int wn   = w & 3;

    const int bid = blockIdx.x;
    const int xcd = bid & 7;
    const int idx = bid >> 3;
    const int row_pan  = (xcd >> 1) * 8 + (idx >> 3);
    const int col_tile = (xcd & 1) * 8 + (idx & 7);
    const int rb0 = row_pan * GBM;
    const int cb0 = col_tile * GBN;

    const int rowA = tid >> 1;
    const int h    = tid & 1;
    const int fr   = (rowA & 3) ^ ((rowA >> 2) & 3);
    const char* gAb = (const char*)Rb + (size_t)(rb0 + rowA) * 1024 + h * 32;
    const char* gBb = (const char*)Cb + (size_t)(cb0 + rowA) * 1024 + h * 32;
    const int wpos0 = rowA * 64 + (((2 * h)     ^ fr) << 4);
    const int wpos1 = rowA * 64 + (((2 * h + 1) ^ fr) << 4);

    const int la = lane & 15, ks = lane >> 4;
    const int fla = (la & 3) ^ ((la >> 2) & 3);
    const int offA = (wm * 128 + la) * 64 + ((ks ^ fla) << 4);
    const int offB = (wn * 64  + la) * 64 + ((ks ^ fla) << 4);

    f32x4 acc[8][4];
    const f32x4 zero = {0.f, 0.f, 0.f, 0.f};
#pragma unroll
    for (int m = 0; m < 8; ++m)
#pragma unroll
        for (int n = 0; n < 4; ++n) acc[m][n] = zero;

    uint4 eA0, eA1, eB0, eB1;
    uint4 oA0, oA1, oB0, oB1;

#define LOADT(rA0, rA1, rB0, rB1, T) do {                    \
        const char* _pa = gAb + (T) * 64;                    \
        rA0 = *(const uint4*)(_pa);                          \
        rA1 = *(const uint4*)(_pa + 16);                     \
        const char* _pb = gBb + (T) * 64;                    \
        rB0 = *(const uint4*)(_pb);                          \
        rB1 = *(const uint4*)(_pb + 16);                     \
    } while (0)

#define ITER(T, rA0, rA1, rB0, rB1, P) do {                               \
        *(uint4*)((char*)&As[P][0] + wpos0) = rA0;                        \
        *(uint4*)((char*)&As[P][0] + wpos1) = rA1;                        \
        *(uint4*)((char*)&Bs[P][0] + wpos0) = rB0;                        \
        *(uint4*)((char*)&Bs[P][0] + wpos1) = rB1;                        \
        if ((T) + 2 < 16) LOADT(rA0, rA1, rB0, rB1, (T) + 2);             \
        asm volatile("s_waitcnt lgkmcnt(0)" ::: "memory");                \
        __builtin_amdgcn_s_barrier();                                     \
        const char* _rA = (const char*)&As[P][0];                         \
        const char* _rB = (const char*)&Bs[P][0];                         \
        bf16x8 av[8], bv[4];                                              \
        _Pragma("unroll")                                                 \
        for (int m = 0; m < 8; ++m) av[m] = *(const bf16x8*)(_rA + offA + m * 1024); \
        _Pragma("unroll")                                                 \
        for (int n = 0; n < 4; ++n) bv[n] = *(const bf16x8*)(_rB + offB + n * 1024); \
        _Pragma("unroll")                                                 \
        for (int m = 0; m < 8; ++m)                                       \
            _Pragma("unroll")                                             \
            for (int n = 0; n < 4; ++n)                                   \
                acc[m][n] = __builtin_amdgcn_mfma_f32_16x16x32_bf16(av[m], bv[n], acc[m][n], 0, 0, 0); \
    } while (0)

    LOADT(eA0, eA1, eB0, eB1, 0);
    LOADT(oA0, oA1, oB0, oB1, 1);

#pragma unroll 1
    for (int tt = 0; tt < 16; tt += 2) {
        ITER(tt,     eA0, eA1, eB0, eB1, 0);
        ITER(tt + 1, oA0, oA1, oB0, oB1, 1);
    }
#undef ITER
#undef LOADT

    __syncthreads();
    Top2 (*mrg)[4] = (Top2 (*)[4])&As[0][0];

    const int rgrp = lane >> 4;
    const int cidx = lane & 15;
#pragma unroll
    for (int m = 0; m < 8; ++m) {
#pragma unroll
        for (int j = 0; j < 4; ++j) {
            float v1 = -INFINITY, v2 = -INFINITY;
            int   i1 = 0x7fffffff, i2 = 0x7fffffff;
#pragma unroll
            for (int n = 0; n < 4; ++n)
                top2_insert(acc[m][n][j], cb0 + wn * 64 + n * 16 + cidx, v1, i1, v2, i2);
            for (int off = 1; off < 16; off <<= 1) {
                float ov1 = __shfl_xor(v1, off); int oi1 = __shfl_xor(i1, off);
                float ov2 = __shfl_xor(v2, off); int oi2 = __shfl_xor(i2, off);
                if (ov1 > v1 || (ov1 == v1 && oi1 < i1)) {
                    float nv2; int ni2; pick_better(v1, i1, ov2, oi2, nv2, ni2);
                    v1 = ov1; i1 = oi1; v2 = nv2; i2 = ni2;
                } else {
                    float nv2; int ni2; pick_better(v2, i2, ov1, oi1, nv2, ni2);
                    v2 = nv2; i2 = ni2;
                }
            }
            if (cidx == 0) {
                Top2 p; p.v1 = v1; p.i1 = i1; p.v2 = v2; p.i2 = i2;
                mrg[wm * 128 + m * 16 + rgrp * 4 + j][wn] = p;
            }
        }
    }
    __syncthreads();
    if (tid < 256) {
        Top2 x0 = mrg[tid][0], x1 = mrg[tid][1];
        float v1 = x0.v1, v2 = x0.v2; int i1 = x0.i1, i2 = x0.i2;
        top2_insert(x1.v1, x1.i1, v1, i1, v2, i2);
        top2_insert(x1.v2, x1.i2, v1, i1, v2, i2);
        Top2 p; p.v1 = v1; p.i1 = i1; p.v2 = v2; p.i2 = i2;
        part[(size_t)(rb0 + tid) * NTB + col_tile * 2] = p;
        Top2 y0 = mrg[tid][2], y1 = mrg[tid][3];
        v1 = y0.v1; v2 = y0.v2; i1 = y0.i1; i2 = y0.i2;
        top2_insert(y1.v1, y1.i1, v1, i1, v2, i2);
        top2_insert(y1.v2, y1.i2, v1, i1, v2, i2);
        p.v1 = v1; p.i1 = i1; p.v2 = v2; p.i2 = i2;
        part[(size_t)(rb0 + tid) * NTB + col_tile * 2 + 1] = p;
    }
}

// ============================ DIAGNOSTIC PROBES ============================
// All write only to the cbb scratch region (overwritten by k_cvt_bf16 later).

// P1: barrier + MFMA floor, register operands only. reps=16.
__global__ __launch_bounds__(512, 2)
void p_mfma_reg(float* __restrict__ junk)
{
    const int tid = threadIdx.x;
    bf16x8 av[8], bv[4];
#pragma unroll
    for (int m = 0; m < 8; ++m)
#pragma unroll
        for (int q = 0; q < 8; ++q)
            ((u16*)&av[m])[q] = f2bf((float)(((tid + m * 7 + q * 3) & 31) - 16) * 0.0625f);
#pragma unroll
    for (int n = 0; n < 4; ++n)
#pragma unroll
        for (int q = 0; q < 8; ++q)
            ((u16*)&bv[n])[q] = f2bf((float)(((tid * 5 + n * 11 + q) & 31) - 16) * 0.0625f);
    f32x4 acc[8][4];
    const f32x4 zero = {0.f, 0.f, 0.f, 0.f};
#pragma unroll
    for (int m = 0; m < 8; ++m)
#pragma unroll
        for (int n = 0; n < 4; ++n) acc[m][n] = zero;
#pragma unroll 1
    for (int rep = 0; rep < 16; ++rep) {
#pragma unroll 1
        for (int t = 0; t < 16; ++t) {
            __builtin_amdgcn_s_barrier();
#pragma unroll
            for (int m = 0; m < 8; ++m)
#pragma unroll
                for (int n = 0; n < 4; ++n)
                    acc[m][n] = __builtin_amdgcn_mfma_f32_16x16x32_bf16(av[m], bv[n], acc[m][n], 0, 0, 0);
        }
    }
    float s = 0.f;
#pragma unroll
    for (int m = 0; m < 8; ++m)
#pragma unroll
        for (int n = 0; n < 4; ++n)
#pragma unroll
            for (int j = 0; j < 4; ++j) s += acc[m][n][j];
    junk[blockIdx.x * 512 + tid] = s;
}

// P2: prefilled-LDS ds_read + MFMA + barrier (no staging, no vmem). reps=8.
__global__ __launch_bounds__(512, 2)
void p_lds_mfma(float* __restrict__ junk)
{
    __shared__ __align__(16) u16 As[2][8192];
    __shared__ __align__(16) u16 Bs[2][8192];
    const int tid  = threadIdx.x;
    const int lane = tid & 63;
    const int w    = tid >> 6;
    const int wm   = w >> 2;
    const int wn   = w & 3;
    const int rowA = tid >> 1;
    const int h    = tid & 1;
    const int fr   = (rowA & 3) ^ ((rowA >> 2) & 3);
    const int wpos0 = rowA * 64 + (((2 * h)     ^ fr) << 4);
    const int wpos1 = rowA * 64 + (((2 * h + 1) ^ fr) << 4);
    uint4 g;
    g.x = tid * 0x01010101u; g.y = g.x ^ 0x5a5a5a5au; g.z = g.x + 77u; g.w = g.x ^ 0x33cc33ccu;
    *(uint4*)((char*)&As[0][0] + wpos0) = g;
    *(uint4*)((char*)&As[0][0] + wpos1) = g;
    *(uint4*)((char*)&As[1][0] + wpos0) = g;
    *(uint4*)((char*)&As[1][0] + wpos1) = g;
    *(uint4*)((char*)&Bs[0][0] + wpos0) = g;
    *(uint4*)((char*)&Bs[0][0] + wpos1) = g;
    *(uint4*)((char*)&Bs[1][0] + wpos0) = g;
    *(uint4*)((char*)&Bs[1][0] + wpos1) = g;
    __syncthreads();

    const int la = lane & 15, ks = lane >> 4;
    const int fla = (la & 3) ^ ((la >> 2) & 3);
    const int offA = (wm * 128 + la) * 64 + ((ks ^ fla) << 4);
    const int offB = (wn * 64  + la) * 64 + ((ks ^ fla) << 4);

    f32x4 acc[8][4];
    const f32x4 zero = {0.f, 0.f, 0.f, 0.f};
#pragma unroll
    for (int m = 0; m < 8; ++m)
#pragma unroll
        for (int n = 0; n < 4; ++n) acc[m][n] = zero;

#pragma unroll 1
    for (int rep = 0; rep < 8; ++rep) {
#pragma unroll 1
        for (int t = 0; t < 16; ++t) {
            const int P = t & 1;
            asm volatile("s_waitcnt lgkmcnt(0)" ::: "memory");
            __builtin_amdgcn_s_barrier();
            const char* _rA = (const char*)&As[P][0];
            const char* _rB = (const char*)&Bs[P][0];
            bf16x8 av[8], bv[4];
#pragma unroll
            for (int m = 0; m < 8; ++m) av[m] = *(const bf16x8*)(_rA + offA + m * 1024);
#pragma unroll
            for (int n = 0; n < 4; ++n) bv[n] = *(const bf16x8*)(_rB + offB + n * 1024);
#pragma unroll
            for (int m = 0; m < 8; ++m)
#pragma unroll
                for (int n = 0; n < 4; ++n)
                    acc[m][n] = __builtin_amdgcn_mfma_f32_16x16x32_bf16(av[m], bv[n], acc[m][n], 0, 0, 0);
        }
    }
    float s = 0.f;
#pragma unroll
    for (int m = 0; m < 8; ++m)
#pragma unroll
        for (int n = 0; n < 4; ++n)
#pragma unroll
            for (int j = 0; j < 4; ++j) s += acc[m][n][j];
    junk[blockIdx.x * 512 + tid] = s;
}

// P3: staging only (global->reg 2 ahead, ds_write, lgkmcnt(0), barrier). reps=8.
__global__ __launch_bounds__(512, 2)
void p_stage(const char* __restrict__ src, float* __restrict__ junk)
{
    __shared__ __align__(16) u16 As[2][8192];
    __shared__ __align__(16) u16 Bs[2][8192];
    const int tid  = threadIdx.x;
    const int bid  = blockIdx.x;
    const int rb0  = (bid & 31) * 256;
    const int cb0  = (bid >> 5) * 256;
    const int rowA = tid >> 1;
    const int h    = tid & 1;
    const int fr   = (rowA & 3) ^ ((rowA >> 2) & 3);
    const char* gAb = src + (size_t)(rb0 + rowA) * 1024 + h * 32;
    const char* gBb = src + (size_t)(4194304) + (size_t)(cb0 + rowA) * 1024 + h * 32;
    const int wpos0 = rowA * 64 + (((2 * h)     ^ fr) << 4);
    const int wpos1 = rowA * 64 + (((2 * h + 1) ^ fr) << 4);

    uint4 eA0, eA1, eB0, eB1, oA0, oA1, oB0, oB1;
#define LOADT(rA0, rA1, rB0, rB1, T) do {                    \
        const char* _pa = gAb + (T) * 64;                    \
        rA0 = *(const uint4*)(_pa);                          \
        rA1 = *(const uint4*)(_pa + 16);                     \
        const char* _pb = gBb + (T) * 64;                    \
        rB0 = *(const uint4*)(_pb);                          \
        rB1 = *(const uint4*)(_pb + 16);                     \
    } while (0)
#define SITER(T, rA0, rA1, rB0, rB1, P) do {                              \
        *(uint4*)((char*)&As[P][0] + wpos0) = rA0;                        \
        *(uint4*)((char*)&As[P][0] + wpos1) = rA1;                        \
        *(uint4*)((char*)&Bs[P][0] + wpos0) = rB0;                        \
        *(uint4*)((char*)&Bs[P][0] + wpos1) = rB1;                        \
        if ((T) + 2 < 16) LOADT(rA0, rA1, rB0, rB1, (T) + 2);             \
        asm volatile("s_waitcnt lgkmcnt(0)" ::: "memory");                \
        __builtin_amdgcn_s_barrier();                                     \
    } while (0)
#pragma unroll 1
    for (int rep = 0; rep < 8; ++rep) {
        LOADT(eA0, eA1, eB0, eB1, 0);
        LOADT(oA0, oA1, oB0, oB1, 1);
#pragma unroll 1
        for (int tt = 0; tt < 16; tt += 2) {
            SITER(tt,     eA0, eA1, eB0, eB1, 0);
            SITER(tt + 1, oA0, oA1, oB0, oB1, 1);
        }
    }
#undef SITER
#undef LOADT
    __syncthreads();
    const float* a = (const float*)&As[0][0];
    junk[bid * 512 + tid] = a[tid] + (float)(eA0.x & 1) + (float)(oB1.w & 1)
                          + (float)(eA1.y & 1) + (float)(eB0.z & 1)
                          + (float)(eB1.x & 1) + (float)(oA0.y & 1)
                          + (float)(oA1.z & 1) + (float)(oB0.w & 1);
}

// P4: full K-loop (stage + reads + MFMA), no epilogue. reps=8.
__global__ __launch_bounds__(512, 2)
void p_noepi(const char* __restrict__ src, float* __restrict__ junk)
{
    __shared__ __align__(16) u16 As[2][8192];
    __shared__ __align__(16) u16 Bs[2][8192];
    const int tid  = threadIdx.x;
    const int lane = tid & 63;
    const int w    = tid >> 6;
    const int wm   = w >> 2;
    const int wn   = w & 3;
    const int bid  = blockIdx.x;
    const int rb0  = (bid & 31) * 256;
    const int cb0  = (bid >> 5) * 256;
    const int rowA = tid >> 1;
    const int h    = tid & 1;
    const int fr   = (rowA & 3) ^ ((rowA >> 2) & 3);
    const char* gAb = src + (size_t)(rb0 + rowA) * 1024 + h * 32;
    const char* gBb = src + (size_t)(4194304) + (size_t)(cb0 + rowA) * 1024 + h * 32;
    const int wpos0 = rowA * 64 + (((2 * h)     ^ fr) << 4);
    const int wpos1 = rowA * 64 + (((2 * h + 1) ^ fr) << 4);
    const int la = lane & 15, ks = lane >> 4;
    const int fla = (la & 3) ^ ((la >> 2) & 3);
    const int offA = (wm * 128 + la) * 64 + ((ks ^ fla) << 4);
    const int offB = (wn * 64  + la) * 64 + ((ks ^ fla) << 4);

    f32x4 acc[8][4];
    const f32x4 zero = {0.f, 0.f, 0.f, 0.f};
#pragma unroll
    for (int m = 0; m < 8; ++m)
#pragma unroll
        for (int n = 0; n < 4; ++n) acc[m][n] = zero;
    uint4 eA0, eA1, eB0, eB1, oA0, oA1, oB0, oB1;

#define LOADT(rA0, rA1, rB0, rB1, T) do {                    \
        const char* _pa = gAb + (T) * 64;                    \
        rA0 = *(const uint4*)(_pa);                          \
        rA1 = *(const uint4*)(_pa + 16);                     \
        const char* _pb = gBb + (T) * 64;                    \
        rB0 = *(const uint4*)(_pb);                          \
        rB1 = *(const uint4*)(_pb + 16);                     \
    } while (0)
#define ITER(T, rA0, rA1, rB0, rB1, P) do {                               \
        *(uint4*)((char*)&As[P][0] + wpos0) = rA0;                        \
        *(uint4*)((char*)&As[P][0] + wpos1) = rA1;                        \
        *(uint4*)((char*)&Bs[P][0] + wpos0) = rB0;                        \
        *(uint4*)((char*)&Bs[P][0] + wpos1) = rB1;                        \
        if ((T) + 2 < 16) LOADT(rA0, rA1, rB0, rB1, (T) + 2);             \
        asm volatile("s_waitcnt lgkmcnt(0)" ::: "memory");                \
        __builtin_amdgcn_s_barrier();                                     \
        const char* _rA = (const char*)&As[P][0];                         \
        const char* _rB = (const char*)&Bs[P][0];                         \
        bf16x8 av[8], bv[4];                                              \
        _Pragma("unroll")                                                 \
        for (int m = 0; m < 8; ++m) av[m] = *(const bf16x8*)(_rA + offA + m * 1024); \
        _Pragma("unroll")                                                 \
        for (int n = 0; n < 4; ++n) bv[n] = *(const bf16x8*)(_rB + offB + n * 1024); \
        _Pragma("unroll")                                                 \
        for (int m = 0; m < 8; ++m)                                       \
            _Pragma("unroll")                                             \
            for (int n = 0; n < 4; ++n)                                   \
                acc[m][n] = __builtin_amdgcn_mfma_f32_16x16x32_bf16(av[m], bv[n], acc[m][n], 0, 0, 0); \
    } while (0)

#pragma unroll 1
    for (int rep = 0; rep < 8; ++rep) {
        LOADT(eA0, eA1, eB0, eB1, 0);
        LOADT(oA0, oA1, oB0, oB1, 1);
#pragma unroll 1
        for (int tt = 0; tt < 16; tt += 2) {
            ITER(tt,     eA0, eA1, eB0, eB1, 0);
            ITER(tt + 1, oA0, oA1, oB0, oB1, 1);
        }
    }
#undef ITER
#undef LOADT
    float s = 0.f;
#pragma unroll
    for (int m = 0; m < 8; ++m)
#pragma unroll
        for (int n = 0; n < 4; ++n)
#pragma unroll
            for (int j = 0; j < 4; ++j) s += acc[m][n][j];
    junk[bid * 512 + tid] = s;
}

// P5: top-2 shfl epilogue only. reps=32.
__global__ __launch_bounds__(512, 2)
void p_epi(Top2* __restrict__ junkpart)
{
    __shared__ Top2 mrg[256][4];
    const int tid  = threadIdx.x;
    const int lane = tid & 63;
    const int w    = tid >> 6;
    const int wm   = w >> 2;
    const int wn   = w & 3;
    const int bid  = blockIdx.x;
    const int rb0  = (bid & 31) * 256;
    const int col_tile = (bid >> 5) & 15;
    const int cb0  = col_tile * 256;

    f32x4 acc[8][4];
#pragma unroll
    for (int m = 0; m < 8; ++m)
#pragma unroll
        for (int n = 0; n < 4; ++n)
#pragma unroll
            for (int j = 0; j < 4; ++j)
                acc[m][n][j] = (float)(((tid * 31 + m * 17 + n * 7 + j * 3) & 255) - 128);

    const int rgrp = lane >> 4;
    const int cidx = lane & 15;
#pragma unroll 1
    for (int rep = 0; rep < 32; ++rep) {
#pragma unroll
        for (int m = 0; m < 8; ++m) {
#pragma unroll
            for (int j = 0; j < 4; ++j) {
                float v1 = -INFINITY, v2 = -INFINITY;
                int   i1 = 0x7fffffff, i2 = 0x7fffffff;
#pragma unroll
                for (int n = 0; n < 4; ++n)
                    top2_insert(acc[m][n][j] + (float)rep, cb0 + wn * 64 + n * 16 + cidx, v1, i1, v2, i2);
                for (int off = 1; off < 16; off <<= 1) {
                    float ov1 = __shfl_xor(v1, off); int oi1 = __shfl_xor(i1, off);
                    float ov2 = __shfl_xor(v2, off); int oi2 = __shfl_xor(i2, off);
                    if (ov1 > v1 || (ov1 == v1 && oi1 < i1)) {
                        float nv2; int ni2; pick_better(v1, i1, ov2, oi2, nv2, ni2);
                        v1 = ov1; i1 = oi1; v2 = nv2; i2 = ni2;
                    } else {
                        float nv2; int ni2; pick_better(v2, i2, ov1, oi1, nv2, ni2);
                        v2 = nv2; i2 = ni2;
                    }
                }
                if (cidx == 0) {
                    Top2 p; p.v1 = v1; p.i1 = i1; p.v2 = v2; p.i2 = i2;
                    mrg[wm * 128 + m * 16 + rgrp * 4 + j][wn] = p;
                }
            }
        }
        __syncthreads();
        if (tid < 256) {
            Top2 x0 = mrg[tid][0], x1 = mrg[tid][1];
            float v1 = x0.v1, v2 = x0.v2; int i1 = x0.i1, i2 = x0.i2;
            top2_insert(x1.v1, x1.i1, v1, i1, v2, i2);
            top2_insert(x1.v2, x1.i2, v1, i1, v2, i2);
            Top2 p; p.v1 = v1; p.i1 = i1; p.v2 = v2; p.i2 = i2;
            junkpart[(size_t)(rb0 + tid) * NTB + col_tile * 2] = p;
            Top2 y0 = mrg[tid][2], y1 = mrg[tid][3];
            v1 = y0.v1; v2 = y0.v2; i1 = y0.i1; i2 = y0.i2;
            top2_insert(y1.v1, y1.i1, v1, i1, v2, i2);
            top2_insert(y1.v2, y1.i2, v1, i1, v2, i2);
            p.v1 = v1; p.i1 = i1; p.v2 = v2; p.i2 = i2;
            junkpart[(size_t)(rb0 + tid) * NTB + col_tile * 2 + 1] = p;
        }
        __syncthreads();
    }
}

// =============================== TAIL KERNELS ===============================
__global__ __launch_bounds__(256)
void k_refine(const Top2* __restrict__ part, const float* __restrict__ CB,
              const float* __restrict__ prevBase, size_t prevStride,
              const float* __restrict__ X, float* __restrict__ out_q,
              float* __restrict__ stack, u16* __restrict__ residb,
              float* __restrict__ out_usage, float* __restrict__ pl,
              int layer)
{
    __shared__ float row[DD];
    __shared__ float candV[64];
    __shared__ int   candI[64];
    __shared__ float s_thr;
    __shared__ float wbv[4];
    __shared__ int   wbi[4];
    __shared__ int   s_best;
    __shared__ float red[256];

    const int b = blockIdx.x;
    const int tid = threadIdx.x;
    const float* pr = prevBase + (size_t)b * prevStride;
    row[tid]       = pr[tid];
    row[tid + 256] = pr[tid + 256];
    if (tid < 64) {
        Top2 p = part[(size_t)b * NTB + (tid >> 1)];
        candV[tid] = (tid & 1) ? p.v2 : p.v1;
        candI[tid] = (tid & 1) ? p.i2 : p.i1;
    }
    __syncthreads();
    if (tid < 64) {
        float v = candV[tid];
        for (int off = 1; off < 64; off <<= 1) v = fmaxf(v, __shfl_xor(v, off));
        if (tid == 0) s_thr = v - MARGIN;
    }
    __syncthreads();
    const float thr = s_thr;

    const int wave = tid >> 6;
    const int lane = tid & 63;
    float bestV = -INFINITY;
    int   bestI = 0x7fffffff;
    for (int s = 0; s < 16; ++s) {
        const int c = wave * 16 + s;
        if (candV[c] < thr) continue;
        const int ci = candI[c];
        const float* cr = CB + (size_t)ci * DD;
        float p = 0.f;
#pragma unroll
        for (int q = 0; q < 8; ++q)
            p = fmaf(row[lane * 8 + q], cr[lane * 8 + q], p);
        for (int off = 32; off >= 1; off >>= 1) p += __shfl_xor(p, off);
        if (p > bestV || (p == bestV && ci < bestI)) { bestV = p; bestI = ci; }
    }
    if (lane == 0) { wbv[wave] = bestV; wbi[wave] = bestI; }
    __syncthreads();
    if (tid == 0) {
        float bv = wbv[0]; int bi = wbi[0];
        for (int k = 1; k < 4; ++k)
            if (wbv[k] > bv || (wbv[k] == bv && wbi[k] < bi)) { bv = wbv[k]; bi = wbi[k]; }
        s_best = bi;
        out_usage[layer * KC + bi] = 1.0f;
    }
    __syncthreads();
    const int bi = s_best;

    const float* cr = CB + (size_t)bi * DD;
    const float rn0 = row[tid]       - cr[tid];
    const float rn1 = row[tid + 256] - cr[tid + 256];
    float* sp = stack + ((size_t)b * NL + layer) * DD;
    sp[tid]       = rn0;
    sp[tid + 256] = rn1;
    residb[(size_t)b * DD + tid]       = f2bf(rn0);
    residb[(size_t)b * DD + tid + 256] = f2bf(rn1);
    if (layer == NL - 1) {
        out_q[(size_t)b * DD + tid]       = X[(size_t)b * DD + tid]       - rn0;
        out_q[(size_t)b * DD + tid + 256] = X[(size_t)b * DD + tid + 256] - rn1;
    }
    red[tid] = rn0 * rn0 + rn1 * rn1;
    __syncthreads();
    for (int st = 128; st > 0; st >>= 1) {
        if (tid < st) red[tid] += red[tid + st];
        __syncthreads();
    }
    if (tid == 0) pl[(size_t)layer * NB + b] = red[0];
}

__global__ __launch_bounds__(256)
void k_cbsq(const float* __restrict__ cb, double* __restrict__ cq)
{
    __shared__ double red[256];
    const size_t n = (size_t)NL * KC * DD;
    double s = 0.0;
    for (size_t i = (size_t)blockIdx.x * blockDim.x + threadIdx.x; i < n;
         i += (size_t)gridDim.x * blockDim.x) {
        const float v = cb[i];
        s += (double)v * (double)v;
    }
    red[threadIdx.x] = s;
    __syncthreads();
    for (int st = 128; st > 0; st >>= 1) {
        if (threadIdx.x < st) red[threadIdx.x] += red[threadIdx.x + st];
        __syncthreads();
    }
    if (threadIdx.x == 0) cq[blockIdx.x] = red[0];
}

__global__ __launch_bounds__(256)
void k_finalize(const float* __restrict__ pl, const double* __restrict__ cq,
                float* __restrict__ out_loss)
{
    __shared__ double red[256];
    const int tid = threadIdx.x;
    double s = 0.0;
    for (int i = tid; i < NL * NB; i += 256) s += (double)pl[i];
    double s2 = 0.0;
    for (int i = tid; i < 1024; i += 256) s2 += cq[i];
    red[tid] = s / ((double)NB * DD) + 0.01 * (s2 / ((double)NL * KC));
    __syncthreads();
    for (int st = 128; st > 0; st >>= 1) {
        if (tid < st) red[tid] += red[tid + st];
        __syncthreads();
    }
    if (tid == 0) out_loss[0] = (float)(red[0] / (double)DD);
}

extern "C" void kernel_launch(void* const* d_in, const int* in_sizes, int n_in,
                              void* d_out, int out_size, void* d_ws, size_t ws_size,
                              hipStream_t stream)
{
    (void)in_sizes; (void)n_in; (void)out_size; (void)ws_size;
    const float* x  = (const float*)d_in[0];
    const float* cb = (const float*)d_in[2];

    float* out       = (float*)d_out;
    float* out_q     = out;
    float* out_loss  = out + (size_t)NB * DD;
    float* out_stack = out_loss + 1;
    float* out_usage = out_stack + (size_t)NB * NL * DD;

    char* ws = (char*)d_ws;
    Top2*  part   = (Top2*)ws;                                // 4 MB
    u16*   residb = (u16*)(ws + ((size_t)4 << 20));           // 8 MB
    u16*   cbb    = (u16*)(ws + ((size_t)12 << 20));          // 4 MB (also probe junk)
    float* pl     = (float*)(ws + ((size_t)16 << 20));
    double* cq    = (double*)(ws + ((size_t)16 << 20) + 131072 + 256);

    float* junkf    = (float*)cbb;    // probe scratch, overwritten by cvt below
    Top2*  junkpart = (Top2*)cbb;

    // ---- diagnostic probes (results unused; cbb rewritten afterwards) ----
    p_mfma_reg<<<512, 512, 0, stream>>>(junkf);
    p_lds_mfma<<<512, 512, 0, stream>>>(junkf);
    p_stage<<<512, 512, 0, stream>>>((const char*)cb, junkf);
    p_noepi<<<512, 512, 0, stream>>>((const char*)cb, junkf);
    p_epi<<<512, 512, 0, stream>>>(junkpart);

    // ---- real pipeline (R5, unchanged) ----
    hipMemsetAsync(out_usage, 0, (size_t)NL * KC * sizeof(float), stream);

    k_cvt_bf16<<<(NB * DD / 4 + 255) / 256, 256, 0, stream>>>(x, residb, NB * DD / 4);
    k_cbsq<<<1024, 256, 0, stream>>>(cb, cq);

    for (int l = 0; l < NL; ++l) {
        const float* cbl = cb + (size_t)l * KC * DD;
        k_cvt_bf16<<<(KC * DD / 4 + 255) / 256, 256, 0, stream>>>(cbl, cbb, KC * DD / 4);
        k_simtop2<<<512, 512, 0, stream>>>(residb, cbb, part);
        const float* prevBase = (l == 0) ? x : (out_stack + (size_t)(l - 1) * DD);
        const size_t prevStride = (l == 0) ? (size_t)DD : (size_t)NL * DD;
        k_refine<<<NB, 256, 0, stream>>>(part, cbl, prevBase, prevStride, x, out_q,
                                         out_stack, residb, out_usage, pl, l);
    }
    k_finalize<<<1, 256, 0, stream>>>(pl, cq, out_loss);
}

// Round 8
// 348.589 us; speedup vs baseline: 11.8969x; 11.8969x over previous
//
#include <hip/hip_runtime.h>
#include <math.h>

#define NB 8192     // batch rows
#define DD 512      // hidden dim
#define KC 4096     // codebook size
#define NL 4        // layers

#define NTB 32      // part[] column tiles (128 codes each)
#define MARGIN 4.0f // bf16-dot candidate margin (>> 2*max bf16 dot error ~0.3)

#define GBM 256
#define GBN 256

typedef __bf16 bf16x8 __attribute__((ext_vector_type(8)));
typedef float  f32x4  __attribute__((ext_vector_type(4)));
typedef unsigned short u16;
typedef unsigned int   u32;

struct Top2 { float v1; int i1; float v2; int i2; };

__device__ __forceinline__ u16 f2bf(float f) {   // RNE fp32 -> bf16
    unsigned u = __float_as_uint(f);
    return (u16)((u + 0x7fffu + ((u >> 16) & 1u)) >> 16);
}

__device__ __forceinline__ u32 umaxu(u32 a, u32 b) { return a > b ? a : b; }
__device__ __forceinline__ u32 uminu(u32 a, u32 b) { return a < b ? a : b; }

// monotonic fp32 -> u32 (order-preserving, incl. negatives)
__device__ __forceinline__ u32 packmono(float f) {
    u32 u = __float_as_uint(f);
    return u ^ (((u32)((int)u >> 31)) | 0x80000000u);
}
__device__ __forceinline__ float unpackv(u32 p) {
    u32 q = p & 0xFFFFFF80u;
    u32 u = (q & 0x80000000u) ? (q ^ 0x80000000u) : ~q;
    return __uint_as_float(u);
}

// fp32 -> bf16 bulk convert (n4 = count/4)
__global__ __launch_bounds__(256)
void k_cvt_bf16(const float* __restrict__ src, u16* __restrict__ dst, int n4)
{
    const int i = blockIdx.x * 256 + threadIdx.x;
    if (i < n4) {
        const float4 f = ((const float4*)src)[i];
        uint2 p;
        p.x = (unsigned)f2bf(f.x) | ((unsigned)f2bf(f.y) << 16);
        p.y = (unsigned)f2bf(f.z) | ((unsigned)f2bf(f.w) << 16);
        ((uint2*)dst)[i] = p;
    }
}

// bf16 MFMA GEMM sim = Rb [NB x DD] @ Cb^T [KC x DD], 256x256 tile, BK=32,
// register-staged 2 K-tiles ahead + single s_barrier per tile (R5 K-loop,
// measured equivalent to 4 other schedules). NEW: branchless packed-u32 top-2
// epilogue (monotonic value bits | inverted local index; umax/umin merges,
// 2 shuffles/stage) replacing the divergent shuffle reduce that p_epi showed
// costs 83us/pass. Fused per-row top-2 per 128-code half -> part[NB][32].
__global__ __launch_bounds__(512, 2)
void k_simtop2(const u16* __restrict__ Rb, const u16* __restrict__ Cb,
               Top2* __restrict__ part /* [NB][NTB] */)
{
    __shared__ __align__(16) u16 As[2][8192];   // [buf][256 rows x 32 k] = 32 KB
    __shared__ __align__(16) u16 Bs[2][8192];   // 32 KB

    const int tid  = threadIdx.x;
    const int lane = tid & 63;
    const int w    = tid >> 6;        // 0..7
    const int wm   = w >> 2;          // 0..1  (row half)
    const int wn   = w & 3;           // 0..3  (col quarter)

    // XCD chunking: 512 blocks -> 8 chunks of 8x8 tiles (A 2MB + B 2MB ~ L2)
    const int bid = blockIdx.x;
    const int xcd = bid & 7;
    const int idx = bid >> 3;                           // 0..63
    const int row_pan  = (xcd >> 1) * 8 + (idx >> 3);   // 0..31
    const int col_tile = (xcd & 1) * 8 + (idx & 7);     // 0..15
    const int rb0 = row_pan * GBM;
    const int cb0 = col_tile * GBN;

    // staging: thread covers row r = tid>>1, k-chunk pair {2h, 2h+1}, h = tid&1.
    // global chunk c stored at LDS chunk c ^ f(r), f(r) = (r&3)^((r>>2)&3).
    const int rowA = tid >> 1;
    const int h    = tid & 1;
    const int fr   = (rowA & 3) ^ ((rowA >> 2) & 3);
    const char* gAb = (const char*)Rb + (size_t)(rb0 + rowA) * 1024 + h * 32;
    const char* gBb = (const char*)Cb + (size_t)(cb0 + rowA) * 1024 + h * 32;
    const int wpos0 = rowA * 64 + (((2 * h)     ^ fr) << 4);
    const int wpos1 = rowA * 64 + (((2 * h + 1) ^ fr) << 4);

    // fragment reads: row = wsub + m*16 + la, chunk = ks ^ f(la)
    const int la = lane & 15, ks = lane >> 4;
    const int fla = (la & 3) ^ ((la >> 2) & 3);
    const int offA = (wm * 128 + la) * 64 + ((ks ^ fla) << 4);
    const int offB = (wn * 64  + la) * 64 + ((ks ^ fla) << 4);

    f32x4 acc[8][4];
    const f32x4 zero = {0.f, 0.f, 0.f, 0.f};
#pragma unroll
    for (int m = 0; m < 8; ++m)
#pragma unroll
        for (int n = 0; n < 4; ++n) acc[m][n] = zero;

    uint4 eA0, eA1, eB0, eB1;   // even-tile staging regs
    uint4 oA0, oA1, oB0, oB1;   // odd-tile staging regs

#define LOADT(rA0, rA1, rB0, rB1, T) do {                    \
        const char* _pa = gAb + (T) * 64;                    \
        rA0 = *(const uint4*)(_pa);                          \
        rA1 = *(const uint4*)(_pa + 16);                     \
        const char* _pb = gBb + (T) * 64;                    \
        rB0 = *(const uint4*)(_pb);                          \
        rB1 = *(const uint4*)(_pb + 16);                     \
    } while (0)

#define ITER(T, rA0, rA1, rB0, rB1, P) do {                               \
        *(uint4*)((char*)&As[P][0] + wpos0) = rA0;                        \
        *(uint4*)((char*)&As[P][0] + wpos1) = rA1;                        \
        *(uint4*)((char*)&Bs[P][0] + wpos0) = rB0;                        \
        *(uint4*)((char*)&Bs[P][0] + wpos1) = rB1;                        \
        if ((T) + 2 < 16) LOADT(rA0, rA1, rB0, rB1, (T) + 2);             \
        asm volatile("s_waitcnt lgkmcnt(0)" ::: "memory");                \
        __builtin_amdgcn_s_barrier();                                     \
        const char* _rA = (const char*)&As[P][0];                         \
        const char* _rB = (const char*)&Bs[P][0];                         \
        bf16x8 av[8], bv[4];                                              \
        _Pragma("unroll")                                                 \
        for (int m = 0; m < 8; ++m) av[m] = *(const bf16x8*)(_rA + offA + m * 1024); \
        _Pragma("unroll")                                                 \
        for (int n = 0; n < 4; ++n) bv[n] = *(const bf16x8*)(_rB + offB + n * 1024); \
        _Pragma("unroll")                                                 \
        for (int m = 0; m < 8; ++m)                                       \
            _Pragma("unroll")                                             \
            for (int n = 0; n < 4; ++n)                                   \
                acc[m][n] = __builtin_amdgcn_mfma_f32_16x16x32_bf16(av[m], bv[n], acc[m][n], 0, 0, 0); \
    } while (0)

    LOADT(eA0, eA1, eB0, eB1, 0);
    LOADT(oA0, oA1, oB0, oB1, 1);

#pragma unroll 1
    for (int tt = 0; tt < 16; tt += 2) {
        ITER(tt,     eA0, eA1, eB0, eB1, 0);
        ITER(tt + 1, oA0, oA1, oB0, oB1, 1);
    }
#undef ITER
#undef LOADT

    __syncthreads();                           // LDS free; reuse As for merge
    uint2 (*mrg)[4] = (uint2 (*)[4])&As[0][0]; // [256 rows][4 wave-cols] = 8 KB

    // ---- branchless packed top-2 epilogue ----
    // C row = (lane>>4)*4 + j (batch), col = lane&15 (code).
    // key = (monotonic(value) & ~0x7F) | (127 - l128), l128 = (wn&1)*64+n*16+cidx
    const int rgrp = lane >> 4;
    const int cidx = lane & 15;
    u32 inv[4];
#pragma unroll
    for (int n = 0; n < 4; ++n)
        inv[n] = (u32)(127 - ((wn & 1) * 64 + n * 16 + cidx));

#pragma unroll
    for (int m = 0; m < 8; ++m) {
#pragma unroll
        for (int j = 0; j < 4; ++j) {
            const u32 p0 = (packmono(acc[m][0][j]) & 0xFFFFFF80u) | inv[0];
            const u32 p1 = (packmono(acc[m][1][j]) & 0xFFFFFF80u) | inv[1];
            const u32 p2 = (packmono(acc[m][2][j]) & 0xFFFFFF80u) | inv[2];
            const u32 p3 = (packmono(acc[m][3][j]) & 0xFFFFFF80u) | inv[3];
            const u32 s1 = umaxu(p0, p1), t1 = uminu(p0, p1);
            const u32 s2 = umaxu(p2, p3), t2 = uminu(p2, p3);
            u32 hi = umaxu(s1, s2);
            u32 lo = umaxu(uminu(s1, s2), umaxu(t1, t2));
#pragma unroll
            for (int off = 1; off < 16; off <<= 1) {
                const u32 oh = (u32)__shfl_xor((int)hi, off);
                const u32 ol = (u32)__shfl_xor((int)lo, off);
                const u32 nh = umaxu(hi, oh);
                lo = umaxu(uminu(hi, oh), umaxu(lo, ol));
                hi = nh;
            }
            if (cidx == 0)
                mrg[wm * 128 + m * 16 + rgrp * 4 + j][wn] = make_uint2(hi, lo);
        }
    }
    __syncthreads();
    if (tid < 256) {   // merge wn pairs -> top-2 per 128-code half (same part format)
#pragma unroll
        for (int tau = 0; tau < 2; ++tau) {
            const uint2 a = mrg[tid][tau * 2], b = mrg[tid][tau * 2 + 1];
            const u32 hi = umaxu(a.x, b.x);
            const u32 lo = umaxu(uminu(a.x, b.x), umaxu(a.y, b.y));
            Top2 p;
            p.v1 = unpackv(hi); p.i1 = cb0 + tau * 128 + 127 - (int)(hi & 127u);
            p.v2 = unpackv(lo); p.i2 = cb0 + tau * 128 + 127 - (int)(lo & 127u);
            part[(size_t)(rb0 + tid) * NTB + col_tile * 2 + tau] = p;
        }
    }
}

// Per row: exact fp32 re-dot of candidates within MARGIN of the bf16 max, argmax,
// residual update (fp32 chain via out_stack + bf16 mirror), per-block loss partial
// (no atomics), usage; layer NL-1 also writes quantized = x - r.
__global__ __launch_bounds__(256)
void k_refine(const Top2* __restrict__ part, const float* __restrict__ CB,
              const float* __restrict__ prevBase, size_t prevStride,
              const float* __restrict__ X, float* __restrict__ out_q,
              float* __restrict__ stack, u16* __restrict__ residb,
              float* __restrict__ out_usage, float* __restrict__ pl,
              int layer)
{
    __shared__ float row[DD];
    __shared__ float candV[64];
    __shared__ int   candI[64];
    __shared__ float s_thr;
    __shared__ float wbv[4];
    __shared__ int   wbi[4];
    __shared__ int   s_best;
    __shared__ float red[256];

    const int b = blockIdx.x;
    const int tid = threadIdx.x;
    const float* pr = prevBase + (size_t)b * prevStride;
    row[tid]       = pr[tid];
    row[tid + 256] = pr[tid + 256];
    if (tid < 64) {
        Top2 p = part[(size_t)b * NTB + (tid >> 1)];
        candV[tid] = (tid & 1) ? p.v2 : p.v1;
        candI[tid] = (tid & 1) ? p.i2 : p.i1;
    }
    __syncthreads();
    if (tid < 64) {
        float v = candV[tid];
        for (int off = 1; off < 64; off <<= 1) v = fmaxf(v, __shfl_xor(v, off));
        if (tid == 0) s_thr = v - MARGIN;
    }
    __syncthreads();
    const float thr = s_thr;

    const int wave = tid >> 6;
    const int lane = tid & 63;
    float bestV = -INFINITY;
    int   bestI = 0x7fffffff;
    for (int s = 0; s < 16; ++s) {
        const int c = wave * 16 + s;
        if (candV[c] < thr) continue;          // wave-uniform skip
        const int ci = candI[c];
        const float* cr = CB + (size_t)ci * DD;
        float p = 0.f;
#pragma unroll
        for (int q = 0; q < 8; ++q)
            p = fmaf(row[lane * 8 + q], cr[lane * 8 + q], p);
        for (int off = 32; off >= 1; off >>= 1) p += __shfl_xor(p, off);
        if (p > bestV || (p == bestV && ci < bestI)) { bestV = p; bestI = ci; }
    }
    if (lane == 0) { wbv[wave] = bestV; wbi[wave] = bestI; }
    __syncthreads();
    if (tid == 0) {
        float bv = wbv[0]; int bi = wbi[0];
        for (int k = 1; k < 4; ++k)
            if (wbv[k] > bv || (wbv[k] == bv && wbi[k] < bi)) { bv = wbv[k]; bi = wbi[k]; }
        s_best = bi;
        out_usage[layer * KC + bi] = 1.0f;
    }
    __syncthreads();
    const int bi = s_best;

    const float* cr = CB + (size_t)bi * DD;
    const float rn0 = row[tid]       - cr[tid];
    const float rn1 = row[tid + 256] - cr[tid + 256];
    float* sp = stack + ((size_t)b * NL + layer) * DD;   // base odd-aligned -> scalar
    sp[tid]       = rn0;
    sp[tid + 256] = rn1;
    residb[(size_t)b * DD + tid]       = f2bf(rn0);
    residb[(size_t)b * DD + tid + 256] = f2bf(rn1);
    if (layer == NL - 1) {
        out_q[(size_t)b * DD + tid]       = X[(size_t)b * DD + tid]       - rn0;
        out_q[(size_t)b * DD + tid + 256] = X[(size_t)b * DD + tid + 256] - rn1;
    }
    red[tid] = rn0 * rn0 + rn1 * rn1;
    __syncthreads();
    for (int st = 128; st > 0; st >>= 1) {
        if (tid < st) red[tid] += red[tid + st];
        __syncthreads();
    }
    if (tid == 0) pl[(size_t)layer * NB + b] = red[0];
}

__global__ __launch_bounds__(256)
void k_cbsq(const float* __restrict__ cb, double* __restrict__ cq)
{
    __shared__ double red[256];
    const size_t n = (size_t)NL * KC * DD;
    double s = 0.0;
    for (size_t i = (size_t)blockIdx.x * blockDim.x + threadIdx.x; i < n;
         i += (size_t)gridDim.x * blockDim.x) {
        const float v = cb[i];
        s += (double)v * (double)v;
    }
    red[threadIdx.x] = s;
    __syncthreads();
    for (int st = 128; st > 0; st >>= 1) {
        if (threadIdx.x < st) red[threadIdx.x] += red[threadIdx.x + st];
        __syncthreads();
    }
    if (threadIdx.x == 0) cq[blockIdx.x] = red[0];
}

__global__ __launch_bounds__(256)
void k_finalize(const float* __restrict__ pl, const double* __restrict__ cq,
                float* __restrict__ out_loss)
{
    __shared__ double red[256];
    const int tid = threadIdx.x;
    double s = 0.0;
    for (int i = tid; i < NL * NB; i += 256) s += (double)pl[i];
    double s2 = 0.0;
    for (int i = tid; i < 1024; i += 256) s2 += cq[i];
    red[tid] = s / ((double)NB * DD) + 0.01 * (s2 / ((double)NL * KC));
    __syncthreads();
    for (int st = 128; st > 0; st >>= 1) {
        if (tid < st) red[tid] += red[tid + st];
        __syncthreads();
    }
    if (tid == 0) out_loss[0] = (float)(red[0] / (double)DD);
}

extern "C" void kernel_launch(void* const* d_in, const int* in_sizes, int n_in,
                              void* d_out, int out_size, void* d_ws, size_t ws_size,
                              hipStream_t stream)
{
    (void)in_sizes; (void)n_in; (void)out_size; (void)ws_size;
    const float* x  = (const float*)d_in[0];
    // d_in[1] = temperature: positive scale, argmax-invariant, soft path cancels -> unused
    const float* cb = (const float*)d_in[2];

    float* out       = (float*)d_out;
    float* out_q     = out;                                   // [NB, DD]
    float* out_loss  = out + (size_t)NB * DD;                 // [1]
    float* out_stack = out_loss + 1;                          // [NB, NL, DD] (fp32 residual chain)
    float* out_usage = out_stack + (size_t)NB * NL * DD;      // [NL, KC]

    char* ws = (char*)d_ws;
    Top2*  part   = (Top2*)ws;                                // 4 MB
    u16*   residb = (u16*)(ws + ((size_t)4 << 20));           // 8 MB bf16 residual mirror
    u16*   cbb    = (u16*)(ws + ((size_t)12 << 20));          // 4 MB bf16 codebook (per layer)
    float* pl     = (float*)(ws + ((size_t)16 << 20));        // NL*NB loss partials (128 KB)
    double* cq    = (double*)(ws + ((size_t)16 << 20) + 131072 + 256); // 1024 cbsq partials

    hipMemsetAsync(out_usage, 0, (size_t)NL * KC * sizeof(float), stream);

    k_cvt_bf16<<<(NB * DD / 4 + 255) / 256, 256, 0, stream>>>(x, residb, NB * DD / 4);
    k_cbsq<<<1024, 256, 0, stream>>>(cb, cq);

    for (int l = 0; l < NL; ++l) {
        const float* cbl = cb + (size_t)l * KC * DD;
        k_cvt_bf16<<<(KC * DD / 4 + 255) / 256, 256, 0, stream>>>(cbl, cbb, KC * DD / 4);
        k_simtop2<<<512, 512, 0, stream>>>(residb, cbb, part);
        const float* prevBase = (l == 0) ? x : (out_stack + (size_t)(l - 1) * DD);
        const size_t prevStride = (l == 0) ? (size_t)DD : (size_t)NL * DD;
        k_refine<<<NB, 256, 0, stream>>>(part, cbl, prevBase, prevStride, x, out_q,
                                         out_stack, residb, out_usage, pl, l);
    }
    k_finalize<<<1, 256, 0, stream>>>(pl, cq, out_loss);
}